// Round 2
// baseline (1142.137 us; speedup 1.0000x reference)
//
#include <hip/hip_runtime.h>
#include <math.h>

#define S_LEN 2048
#define HID_DIM 2048
#define NH 16
#define NKVH 4
#define HD 128
#define QD (NH*HD)    // 2048
#define KD (NKVH*HD)  // 512

// ---------------------------------------------------------------------------
// NT GEMM: C[m][n] = scale * sum_k A[m][k] * B[n][k], optional LSQ epilogue.
// qmode: 0 = none, 1 = sym (clip -128..127), 2 = asym (clip 0..255)
// causal: skip blocks entirely above the diagonal (scores use-case)
// batching: A += z*sA ; B += (z/divB)*sB ; C += z*sC
// ---------------------------------------------------------------------------
__global__ __launch_bounds__(256)
void gemm_nt(const float* __restrict__ A, int lda, long long sA,
             const float* __restrict__ B, int ldb, long long sB, int divB,
             float* __restrict__ C, int ldc, long long sC,
             int K, float scale, int qmode, const float* __restrict__ sPtr,
             int causal)
{
    int bz = blockIdx.z;
    A += (long long)bz * sA;
    B += (long long)(bz / divB) * sB;
    C += (long long)bz * sC;
    int m0 = blockIdx.y * 64, n0 = blockIdx.x * 64;
    if (causal && (m0 + 63 < n0)) return;

    __shared__ float As[16][68];
    __shared__ float Bs[16][68];

    int tid = threadIdx.x;
    int tx = tid & 15, ty = tid >> 4;
    int lr = tid >> 2;          // 0..63 row within tile
    int lk = (tid & 3) * 4;     // 0,4,8,12 k within tile

    float acc[4][4] = {};

    for (int k0 = 0; k0 < K; k0 += 16) {
        float4 av = *(const float4*)&A[(long long)(m0 + lr) * lda + k0 + lk];
        float4 bv = *(const float4*)&B[(long long)(n0 + lr) * ldb + k0 + lk];
        __syncthreads();
        As[lk+0][lr] = av.x; As[lk+1][lr] = av.y; As[lk+2][lr] = av.z; As[lk+3][lr] = av.w;
        Bs[lk+0][lr] = bv.x; Bs[lk+1][lr] = bv.y; Bs[lk+2][lr] = bv.z; Bs[lk+3][lr] = bv.w;
        __syncthreads();
        #pragma unroll
        for (int kk = 0; kk < 16; ++kk) {
            float4 a4 = *(const float4*)&As[kk][ty*4];
            float4 b4 = *(const float4*)&Bs[kk][tx*4];
            float ar[4] = {a4.x, a4.y, a4.z, a4.w};
            float br[4] = {b4.x, b4.y, b4.z, b4.w};
            #pragma unroll
            for (int i = 0; i < 4; ++i)
                #pragma unroll
                for (int j = 0; j < 4; ++j)
                    acc[i][j] = fmaf(ar[i], br[j], acc[i][j]);
        }
    }

    float sv = sPtr ? fabsf(sPtr[0]) : 1.0f;
    #pragma unroll
    for (int i = 0; i < 4; ++i) {
        int m = m0 + ty*4 + i;
        float vals[4];
        #pragma unroll
        for (int j = 0; j < 4; ++j) {
            float v = acc[i][j] * scale;
            if (qmode == 1) {
                float t = fminf(fmaxf(v / sv, -128.f), 127.f);
                v = rintf(t) * sv;
            } else if (qmode == 2) {
                float t = fminf(fmaxf(v / sv, 0.f), 255.f);
                v = rintf(t) * sv;
            }
            vals[j] = v;
        }
        float4 o = {vals[0], vals[1], vals[2], vals[3]};
        *(float4*)&C[(long long)m * ldc + n0 + tx*4] = o;
    }
}

// ---------------------------------------------------------------------------
// NN GEMM: C[m][n] = scale * sum_k A[m][k] * B[k][n], optional LSQ epilogue.
// triA: A is lower-triangular by rows (attn) -> K loop capped at m0+64.
// ---------------------------------------------------------------------------
__global__ __launch_bounds__(256)
void gemm_nn(const float* __restrict__ A, int lda, long long sA,
             const float* __restrict__ B, int ldb, long long sB, int divB,
             float* __restrict__ C, int ldc, long long sC,
             int K, float scale, int qmode, const float* __restrict__ sPtr,
             int triA)
{
    int bz = blockIdx.z;
    A += (long long)bz * sA;
    B += (long long)(bz / divB) * sB;
    C += (long long)bz * sC;
    int m0 = blockIdx.y * 64, n0 = blockIdx.x * 64;
    int Keff = triA ? min(K, m0 + 64) : K;

    __shared__ float As[16][68];
    __shared__ float Bs[16][68];

    int tid = threadIdx.x;
    int tx = tid & 15, ty = tid >> 4;
    int lr = tid >> 2;          // A-tile row
    int lk = (tid & 3) * 4;     // A-tile k
    int kbr = tid >> 4;         // B-tile k row 0..15
    int nbc = (tid & 15) * 4;   // B-tile n col

    float acc[4][4] = {};

    for (int k0 = 0; k0 < Keff; k0 += 16) {
        float4 av = *(const float4*)&A[(long long)(m0 + lr) * lda + k0 + lk];
        float4 bv = *(const float4*)&B[(long long)(k0 + kbr) * ldb + n0 + nbc];
        __syncthreads();
        As[lk+0][lr] = av.x; As[lk+1][lr] = av.y; As[lk+2][lr] = av.z; As[lk+3][lr] = av.w;
        *(float4*)&Bs[kbr][nbc] = bv;
        __syncthreads();
        #pragma unroll
        for (int kk = 0; kk < 16; ++kk) {
            float4 a4 = *(const float4*)&As[kk][ty*4];
            float4 b4 = *(const float4*)&Bs[kk][tx*4];
            float ar[4] = {a4.x, a4.y, a4.z, a4.w};
            float br[4] = {b4.x, b4.y, b4.z, b4.w};
            #pragma unroll
            for (int i = 0; i < 4; ++i)
                #pragma unroll
                for (int j = 0; j < 4; ++j)
                    acc[i][j] = fmaf(ar[i], br[j], acc[i][j]);
        }
    }

    float sv = sPtr ? fabsf(sPtr[0]) : 1.0f;
    #pragma unroll
    for (int i = 0; i < 4; ++i) {
        int m = m0 + ty*4 + i;
        float vals[4];
        #pragma unroll
        for (int j = 0; j < 4; ++j) {
            float v = acc[i][j] * scale;
            if (qmode == 1) {
                float t = fminf(fmaxf(v / sv, -128.f), 127.f);
                v = rintf(t) * sv;
            } else if (qmode == 2) {
                float t = fminf(fmaxf(v / sv, 0.f), 255.f);
                v = rintf(t) * sv;
            }
            vals[j] = v;
        }
        float4 o = {vals[0], vals[1], vals[2], vals[3]};
        *(float4*)&C[(long long)m * ldc + n0 + tx*4] = o;
    }
}

// ---------------------------------------------------------------------------
// RoPE + transpose: in [S][nh*HD] (already LSQ-quantized) -> out [nh][S][HD]
// doRope=0: pure transpose (v path)
// ---------------------------------------------------------------------------
__global__ void rope_kernel(const float* __restrict__ in,
                            const float* __restrict__ cosT,
                            const float* __restrict__ sinT,
                            float* __restrict__ out, int nh, int doRope)
{
    long long idx = (long long)blockIdx.x * 256 + threadIdx.x;
    int d = idx & (HD - 1);
    long long t = idx >> 7;      // s*nh + h
    int h = (int)(t % nh);
    int s = (int)(t / nh);
    float x = in[idx];
    float o;
    if (doRope) {
        float other = (d < 64) ? -in[idx + 64] : in[idx - 64];
        o = x * cosT[s * HD + d] + other * sinT[s * HD + d];
    } else {
        o = x;
    }
    out[((long long)h * S_LEN + s) * HD + d] = o;
}

// ---------------------------------------------------------------------------
// Row softmax + LSQ(asym, s_attn) in place on attn region.
// One block per (head, row). Also zero-fills the masked upper triangle.
// ---------------------------------------------------------------------------
__global__ __launch_bounds__(256)
void softmax_quant(float* __restrict__ attn, const float* __restrict__ sPtr)
{
    int row = blockIdx.x;            // h*S + q
    int q = row & (S_LEN - 1);
    float* p = attn + (long long)row * S_LEN;
    int n = q + 1;
    int tid = threadIdx.x;

    __shared__ float buf[S_LEN];
    __shared__ float swm[4];
    __shared__ float sws[4];

    float mx = -INFINITY;
    for (int i = tid; i < n; i += 256) {
        float v = p[i];
        buf[i] = v;
        mx = fmaxf(mx, v);
    }
    #pragma unroll
    for (int o = 32; o; o >>= 1) mx = fmaxf(mx, __shfl_xor(mx, o));
    if ((tid & 63) == 0) swm[tid >> 6] = mx;
    __syncthreads();
    mx = fmaxf(fmaxf(swm[0], swm[1]), fmaxf(swm[2], swm[3]));

    float lsum = 0.f;
    for (int i = tid; i < n; i += 256) {
        float e = expf(buf[i] - mx);
        buf[i] = e;
        lsum += e;
    }
    #pragma unroll
    for (int o = 32; o; o >>= 1) lsum += __shfl_xor(lsum, o);
    if ((tid & 63) == 0) sws[tid >> 6] = lsum;
    __syncthreads();
    float tot = sws[0] + sws[1] + sws[2] + sws[3];

    float sa = fabsf(sPtr[0]);
    for (int i = tid; i < n; i += 256) {
        float pr = buf[i] / tot;
        float t = fminf(fmaxf(pr / sa, 0.f), 255.f);
        p[i] = rintf(t) * sa;
    }
    for (int i = tid; i < S_LEN; i += 256)
        if (i >= n) p[i] = 0.f;
}

extern "C" void kernel_launch(void* const* d_in, const int* in_sizes, int n_in,
                              void* d_out, int out_size, void* d_ws, size_t ws_size,
                              hipStream_t stream)
{
    const float* hs    = (const float*)d_in[0];
    const float* Wq    = (const float*)d_in[1];
    const float* Wk    = (const float*)d_in[2];
    const float* Wv    = (const float*)d_in[3];
    const float* Wo    = (const float*)d_in[4];
    const float* s_q   = (const float*)d_in[5];
    const float* s_k   = (const float*)d_in[6];
    const float* s_v   = (const float*)d_in[7];
    const float* s_at  = (const float*)d_in[8];
    const float* s_out = (const float*)d_in[9];
    const float* cosT  = (const float*)d_in[10];
    const float* sinT  = (const float*)d_in[11];
    // d_in[12] = attention_mask: pure causal, applied structurally.

    float* out  = (float*)d_out;                         // [S][2048]
    float* attn = out + (long long)S_LEN * HID_DIM;      // [16][S][S]

    // Raw (pre-rope) q/k/v live in the attn region of d_out: consumed before
    // scores overwrite that region.
    float* qraw = attn;                                  // S*QD
    float* kraw = qraw + (long long)S_LEN * QD;          // S*KD
    float* vraw = kraw + (long long)S_LEN * KD;          // S*KD

    // ws: buffers alive during/after scores. 10.5M floats = 42 MB.
    float* ws    = (float*)d_ws;
    float* qrope = ws;                                   // NH*S*HD
    float* krope = qrope + (long long)NH * S_LEN * HD;   // NKVH*S*HD
    float* vt    = krope + (long long)NKVH * S_LEN * HD; // NKVH*S*HD
    float* ao    = vt + (long long)NKVH * S_LEN * HD;    // S*QD

    dim3 blk(256);
    const float iscale = 1.0f / sqrtf((float)HD);

    // 1) QKV projections (f32, fused LSQ sym quant)
    gemm_nt<<<dim3(QD/64, S_LEN/64, 1), blk, 0, stream>>>(
        hs, HID_DIM, 0, Wq, HID_DIM, 0, 1, qraw, QD, 0, HID_DIM, 1.f, 1, s_q, 0);
    gemm_nt<<<dim3(KD/64, S_LEN/64, 1), blk, 0, stream>>>(
        hs, HID_DIM, 0, Wk, HID_DIM, 0, 1, kraw, KD, 0, HID_DIM, 1.f, 1, s_k, 0);
    gemm_nt<<<dim3(KD/64, S_LEN/64, 1), blk, 0, stream>>>(
        hs, HID_DIM, 0, Wv, HID_DIM, 0, 1, vraw, KD, 0, HID_DIM, 1.f, 1, s_v, 0);

    // 2) RoPE (q,k) + head-major transpose; v transpose only
    rope_kernel<<<(S_LEN*QD)/256, blk, 0, stream>>>(qraw, cosT, sinT, qrope, NH, 1);
    rope_kernel<<<(S_LEN*KD)/256, blk, 0, stream>>>(kraw, cosT, sinT, krope, NKVH, 1);
    rope_kernel<<<(S_LEN*KD)/256, blk, 0, stream>>>(vraw, cosT, sinT, vt, NKVH, 0);

    // 3) scores = q @ k^T / sqrt(HD) into attn region (causal blocks only)
    gemm_nt<<<dim3(S_LEN/64, S_LEN/64, NH), blk, 0, stream>>>(
        qrope, HD, (long long)S_LEN*HD,
        krope, HD, (long long)S_LEN*HD, NH/NKVH,
        attn, S_LEN, (long long)S_LEN*S_LEN,
        HD, iscale, 0, nullptr, 1);

    // 4) softmax + LSQ(asym, s_attn) in place; zero upper triangle
    softmax_quant<<<NH*S_LEN, blk, 0, stream>>>(attn, s_at);

    // 5) out_head = attn @ v, LSQ(asym, s_out), stored as [s][h*HD+d]
    gemm_nn<<<dim3(HD/64, S_LEN/64, NH), blk, 0, stream>>>(
        attn, S_LEN, (long long)S_LEN*S_LEN,
        vt, HD, (long long)S_LEN*HD, NH/NKVH,
        ao, QD, HD,
        S_LEN, 1.f, 2, s_out, 1);

    // 6) final projection: out = ao @ Wo^T
    gemm_nt<<<dim3(HID_DIM/64, S_LEN/64, 1), blk, 0, stream>>>(
        ao, QD, 0, Wo, QD, 0, 1, out, HID_DIM, 0, QD, 1.f, 0, nullptr, 0);
}

// Round 3
// 736.211 us; speedup vs baseline: 1.5514x; 1.5514x over previous
//
#include <hip/hip_runtime.h>
#include <math.h>

#define S_LEN 2048
#define HID_DIM 2048
#define NH 16
#define NKVH 4
#define HD 128
#define QD (NH*HD)    // 2048
#define KD (NKVH*HD)  // 512

typedef _Float16 half8_t __attribute__((ext_vector_type(8)));
typedef _Float16 half4_t __attribute__((ext_vector_type(4)));
typedef float f32x4 __attribute__((ext_vector_type(4)));

#define BM 128
#define BN 128
#define BK 32
#define LDT 40   // padded LDS row length in f16 (breaks 16-way bank conflict)

// ---------------------------------------------------------------------------
// Split-f16 MFMA GEMM, NT: C[m][n] = se * sum_k A[m][k]*B[n][k]
// SA/SB = 1: operand converted to single f16 (must be exact-representable)
// SA/SB = 2: operand split into f16 hi+lo; passes = hihi + hi*lo + lo*hi
// preA/preB: scalar premultiplier (from device scalar, optional inverse)
//            applied BEFORE f16 conversion (recovers exact integers).
// epilogue: se = scale_c * |sc1| * |sc2|; qmode 0 none / 1 sym / 2 asym;
//           storeInt: store the integer code instead of code*s.
// causal: skip blocks fully above diagonal. triK: K capped at m0+BM.
// ---------------------------------------------------------------------------
template<int SA, int SB>
__global__ __launch_bounds__(256)
void gemm_mfma(const float* __restrict__ A, int lda, long long strA,
               const float* __restrict__ B, int ldb, long long strB, int divB,
               float* __restrict__ C, int ldc, long long strC,
               int K, float scale_c,
               const float* preAp, int invA,
               const float* preBp, int invB,
               const float* sc1, const float* sc2,
               int qmode, const float* sPtr, int storeInt,
               int causal, int triK)
{
    int bz = blockIdx.z;
    A += (long long)bz * strA;
    B += (long long)(bz / divB) * strB;
    C += (long long)bz * strC;
    int m0 = blockIdx.y * BM, n0 = blockIdx.x * BN;
    if (causal && n0 > m0 + (BM - 1)) return;
    int Keff = K;
    if (triK && (m0 + BM) < Keff) Keff = m0 + BM;

    float preA = 1.f, preB = 1.f;
    if (preAp) { float s = fabsf(preAp[0]); preA = invA ? 1.f / s : s; }
    if (preBp) { float s = fabsf(preBp[0]); preB = invB ? 1.f / s : s; }

    __shared__ _Float16 Ah[BM][LDT];
    __shared__ _Float16 Bh[BN][LDT];
    __shared__ _Float16 Al[SA == 2 ? BM : 1][SA == 2 ? LDT : 1];
    __shared__ _Float16 Bl[SB == 2 ? BN : 1][SB == 2 ? LDT : 1];

    int t = threadIdx.x;
    int srow = t >> 3;            // 0..31
    int sk = (t & 7) * 4;         // 0,4,...,28
    int w = t >> 6, lane = t & 63;
    int wm = (w >> 1) * 64, wn = (w & 1) * 64;
    int lr = lane & 15, lg = lane >> 4;

    f32x4 acc[4][4];
    #pragma unroll
    for (int i = 0; i < 4; ++i)
        #pragma unroll
        for (int j = 0; j < 4; ++j)
            acc[i][j] = (f32x4){0.f, 0.f, 0.f, 0.f};

    for (int k0 = 0; k0 < Keff; k0 += BK) {
        f32x4 av[4], bv[4];
        #pragma unroll
        for (int r = 0; r < 4; ++r) {
            av[r] = *(const f32x4*)&A[(long long)(m0 + srow + 32 * r) * lda + k0 + sk];
            bv[r] = *(const f32x4*)&B[(long long)(n0 + srow + 32 * r) * ldb + k0 + sk];
        }
        __syncthreads();   // previous tile fully consumed
        #pragma unroll
        for (int r = 0; r < 4; ++r) {
            int row = srow + 32 * r;
            half4_t ah, al, bh, bl;
            #pragma unroll
            for (int e = 0; e < 4; ++e) {
                float x = av[r][e] * preA;
                _Float16 h = (_Float16)x;
                ah[e] = h;
                if constexpr (SA == 2) al[e] = (_Float16)(x - (float)h);
                float y = bv[r][e] * preB;
                _Float16 g = (_Float16)y;
                bh[e] = g;
                if constexpr (SB == 2) bl[e] = (_Float16)(y - (float)g);
            }
            *(half4_t*)&Ah[row][sk] = ah;
            *(half4_t*)&Bh[row][sk] = bh;
            if constexpr (SA == 2) *(half4_t*)&Al[row][sk] = al;
            if constexpr (SB == 2) *(half4_t*)&Bl[row][sk] = bl;
        }
        __syncthreads();

        half8_t afh[4], bfh[4];
        #pragma unroll
        for (int i = 0; i < 4; ++i) {
            afh[i] = *(const half8_t*)&Ah[wm + i * 16 + lr][lg * 8];
            bfh[i] = *(const half8_t*)&Bh[wn + i * 16 + lr][lg * 8];
        }
        #pragma unroll
        for (int i = 0; i < 4; ++i)
            #pragma unroll
            for (int j = 0; j < 4; ++j)
                acc[i][j] = __builtin_amdgcn_mfma_f32_16x16x32_f16(afh[i], bfh[j], acc[i][j], 0, 0, 0);
        if constexpr (SB == 2) {
            half8_t bfl[4];
            #pragma unroll
            for (int j = 0; j < 4; ++j)
                bfl[j] = *(const half8_t*)&Bl[wn + j * 16 + lr][lg * 8];
            #pragma unroll
            for (int i = 0; i < 4; ++i)
                #pragma unroll
                for (int j = 0; j < 4; ++j)
                    acc[i][j] = __builtin_amdgcn_mfma_f32_16x16x32_f16(afh[i], bfl[j], acc[i][j], 0, 0, 0);
        }
        if constexpr (SA == 2) {
            half8_t afl[4];
            #pragma unroll
            for (int i = 0; i < 4; ++i)
                afl[i] = *(const half8_t*)&Al[wm + i * 16 + lr][lg * 8];
            #pragma unroll
            for (int i = 0; i < 4; ++i)
                #pragma unroll
                for (int j = 0; j < 4; ++j)
                    acc[i][j] = __builtin_amdgcn_mfma_f32_16x16x32_f16(afl[i], bfh[j], acc[i][j], 0, 0, 0);
        }
    }

    float se = scale_c;
    if (sc1) se *= fabsf(sc1[0]);
    if (sc2) se *= fabsf(sc2[0]);
    float sv = sPtr ? fabsf(sPtr[0]) : 1.f;

    #pragma unroll
    for (int i = 0; i < 4; ++i)
        #pragma unroll
        for (int j = 0; j < 4; ++j)
            #pragma unroll
            for (int r = 0; r < 4; ++r) {
                long long row = m0 + wm + i * 16 + lg * 4 + r;
                long long col = n0 + wn + j * 16 + lr;
                float v = acc[i][j][r] * se;
                if (qmode == 1) {
                    v = rintf(fminf(fmaxf(v / sv, -128.f), 127.f)) * sv;
                } else if (qmode == 2) {
                    float u = rintf(fminf(fmaxf(v / sv, 0.f), 255.f));
                    v = storeInt ? u : u * sv;
                }
                C[row * (long long)ldc + col] = v;
            }
}

// ---------------------------------------------------------------------------
// RoPE + transpose: in [S][nh*HD] -> out [nh][S][HD]
// ---------------------------------------------------------------------------
__global__ void rope_kernel(const float* __restrict__ in,
                            const float* __restrict__ cosT,
                            const float* __restrict__ sinT,
                            float* __restrict__ out, int nh)
{
    long long idx = (long long)blockIdx.x * 256 + threadIdx.x;
    int d = idx & (HD - 1);
    long long tt = idx >> 7;     // s*nh + h
    int h = (int)(tt % nh);
    int s = (int)(tt / nh);
    float x = in[idx];
    float other = (d < 64) ? -in[idx + 64] : in[idx - 64];
    float o = x * cosT[s * HD + d] + other * sinT[s * HD + d];
    out[((long long)h * S_LEN + s) * HD + d] = o;
}

// ---------------------------------------------------------------------------
// v transpose: vraw [S][KVH*HD] / s_v  ->  vtT [kvh][HD][S] (exact ints)
// ---------------------------------------------------------------------------
__global__ __launch_bounds__(256)
void transpose_v(const float* __restrict__ in, float* __restrict__ outp,
                 const float* __restrict__ sPtr)
{
    __shared__ float tile[64][65];
    int s0 = blockIdx.x * 64, d0 = blockIdx.y * 64, h = blockIdx.z;
    float inv = 1.f / fabsf(sPtr[0]);
    int t = threadIdx.x;
    int rr = t >> 4, cc = (t & 15) * 4;
    #pragma unroll
    for (int r = 0; r < 4; ++r) {
        const float* src = &in[(long long)(s0 + rr + 16 * r) * KD + h * HD + d0 + cc];
        f32x4 v = *(const f32x4*)src;
        tile[rr + 16 * r][cc + 0] = v[0] * inv;
        tile[rr + 16 * r][cc + 1] = v[1] * inv;
        tile[rr + 16 * r][cc + 2] = v[2] * inv;
        tile[rr + 16 * r][cc + 3] = v[3] * inv;
    }
    __syncthreads();
    #pragma unroll
    for (int r = 0; r < 4; ++r) {
        int dr = rr + 16 * r;
        f32x4 o = { tile[cc + 0][dr], tile[cc + 1][dr], tile[cc + 2][dr], tile[cc + 3][dr] };
        *(f32x4*)&outp[((long long)h * HD + d0 + dr) * S_LEN + s0 + cc] = o;
    }
}

// ---------------------------------------------------------------------------
// Row softmax + LSQ(asym, s_attn) in place; zero-fills upper triangle.
// ---------------------------------------------------------------------------
__global__ __launch_bounds__(256)
void softmax_quant(float* __restrict__ attn, const float* __restrict__ sPtr)
{
    int row = blockIdx.x;            // h*S + q
    int q = row & (S_LEN - 1);
    float* p = attn + (long long)row * S_LEN;
    int n = q + 1;
    int tid = threadIdx.x;

    __shared__ float buf[S_LEN];
    __shared__ float swm[4];
    __shared__ float sws[4];

    float mx = -INFINITY;
    for (int i = tid; i < n; i += 256) {
        float v = p[i];
        buf[i] = v;
        mx = fmaxf(mx, v);
    }
    #pragma unroll
    for (int o = 32; o; o >>= 1) mx = fmaxf(mx, __shfl_xor(mx, o));
    if ((tid & 63) == 0) swm[tid >> 6] = mx;
    __syncthreads();
    mx = fmaxf(fmaxf(swm[0], swm[1]), fmaxf(swm[2], swm[3]));

    float lsum = 0.f;
    for (int i = tid; i < n; i += 256) {
        float e = expf(buf[i] - mx);
        buf[i] = e;
        lsum += e;
    }
    #pragma unroll
    for (int o = 32; o; o >>= 1) lsum += __shfl_xor(lsum, o);
    if ((tid & 63) == 0) sws[tid >> 6] = lsum;
    __syncthreads();
    float tot = sws[0] + sws[1] + sws[2] + sws[3];

    float sa = fabsf(sPtr[0]);
    for (int i = tid; i < n; i += 256) {
        float pr = buf[i] / tot;
        float t = fminf(fmaxf(pr / sa, 0.f), 255.f);
        p[i] = rintf(t) * sa;
    }
    for (int i = tid; i < S_LEN; i += 256)
        if (i >= n) p[i] = 0.f;
}

extern "C" void kernel_launch(void* const* d_in, const int* in_sizes, int n_in,
                              void* d_out, int out_size, void* d_ws, size_t ws_size,
                              hipStream_t stream)
{
    const float* hs    = (const float*)d_in[0];
    const float* Wq    = (const float*)d_in[1];
    const float* Wk    = (const float*)d_in[2];
    const float* Wv    = (const float*)d_in[3];
    const float* Wo    = (const float*)d_in[4];
    const float* s_q   = (const float*)d_in[5];
    const float* s_k   = (const float*)d_in[6];
    const float* s_v   = (const float*)d_in[7];
    const float* s_at  = (const float*)d_in[8];
    const float* s_out = (const float*)d_in[9];
    const float* cosT  = (const float*)d_in[10];
    const float* sinT  = (const float*)d_in[11];
    // d_in[12] = attention_mask: pure causal, applied structurally.

    float* out  = (float*)d_out;                         // [S][2048]
    float* attn = out + (long long)S_LEN * HID_DIM;      // [16][S][S]

    // Pre-rope q/k/v parked in the attn region (consumed before scores).
    float* qraw = attn;                                  // S*QD
    float* kraw = qraw + (long long)S_LEN * QD;          // S*KD
    float* vraw = kraw + (long long)S_LEN * KD;          // S*KD

    float* ws    = (float*)d_ws;
    float* qrope = ws;                                   // NH*S*HD   (16 MB)
    float* krope = qrope + (long long)NH * S_LEN * HD;   // NKVH*S*HD (4 MB)
    float* vtT   = krope + (long long)NKVH * S_LEN * HD; // NKVH*HD*S (4 MB)
    float* ao    = vtT + (long long)NKVH * S_LEN * HD;   // S*QD      (16 MB)

    dim3 blk(256);
    const float iscale = 0.08838834764831845f;  // 1/sqrt(128)

    // 1) QKV projections: f16-split x3 MFMA, fused LSQ sym quant
    gemm_mfma<2,2><<<dim3(QD/BN, S_LEN/BM, 1), blk, 0, stream>>>(
        hs, HID_DIM, 0, Wq, HID_DIM, 0, 1, qraw, QD, 0,
        HID_DIM, 1.f, nullptr,0, nullptr,0, nullptr,nullptr, 1, s_q, 0, 0, 0);
    gemm_mfma<2,2><<<dim3(KD/BN, S_LEN/BM, 1), blk, 0, stream>>>(
        hs, HID_DIM, 0, Wk, HID_DIM, 0, 1, kraw, KD, 0,
        HID_DIM, 1.f, nullptr,0, nullptr,0, nullptr,nullptr, 1, s_k, 0, 0, 0);
    gemm_mfma<2,2><<<dim3(KD/BN, S_LEN/BM, 1), blk, 0, stream>>>(
        hs, HID_DIM, 0, Wv, HID_DIM, 0, 1, vraw, KD, 0,
        HID_DIM, 1.f, nullptr,0, nullptr,0, nullptr,nullptr, 1, s_v, 0, 0, 0);

    // 2) RoPE q,k ; v transposed to [kvh][HD][S] as exact ints (/s_v)
    rope_kernel<<<(S_LEN*QD)/256, blk, 0, stream>>>(qraw, cosT, sinT, qrope, NH);
    rope_kernel<<<(S_LEN*KD)/256, blk, 0, stream>>>(kraw, cosT, sinT, krope, NKVH);
    transpose_v<<<dim3(S_LEN/64, HD/64, NKVH), blk, 0, stream>>>(vraw, vtT, s_v);

    // 3) scores = q@k^T/sqrt(HD) (f16-split x3, causal block skip)
    gemm_mfma<2,2><<<dim3(S_LEN/BN, S_LEN/BM, NH), blk, 0, stream>>>(
        qrope, HD, (long long)S_LEN*HD,
        krope, HD, (long long)S_LEN*HD, NH/NKVH,
        attn, S_LEN, (long long)S_LEN*S_LEN,
        HD, iscale, nullptr,0, nullptr,0, nullptr,nullptr, 0, nullptr, 0, 1, 0);

    // 4) softmax + LSQ(asym)
    softmax_quant<<<NH*S_LEN, blk, 0, stream>>>(attn, s_at);

    // 5) PV: exact integer f16 MFMA, single pass; stores ui codes into ao
    gemm_mfma<1,1><<<dim3(1, S_LEN/BM, NH), blk, 0, stream>>>(
        attn, S_LEN, (long long)S_LEN*S_LEN,
        vtT, S_LEN, (long long)HD*S_LEN, NH/NKVH,
        ao, QD, HD,
        S_LEN, 1.f, s_at,1, nullptr,0, s_at, s_v, 2, s_out, 1, 0, 1);

    // 6) out = (ao_codes @ Wo^T) * s_out  (A exact f16 ints, B split x2)
    gemm_mfma<1,2><<<dim3(HID_DIM/BN, S_LEN/BM, 1), blk, 0, stream>>>(
        ao, QD, 0, Wo, QD, 0, 1, out, HID_DIM, 0,
        QD, 1.f, nullptr,0, nullptr,0, s_out,nullptr, 0, nullptr, 0, 0, 0);
}

// Round 4
// 637.552 us; speedup vs baseline: 1.7914x; 1.1547x over previous
//
#include <hip/hip_runtime.h>
#include <math.h>

#define S_LEN 2048
#define HID_DIM 2048
#define NH 16
#define NKVH 4
#define HD 128
#define QD (NH*HD)    // 2048
#define KD (NKVH*HD)  // 512

typedef _Float16 half8_t __attribute__((ext_vector_type(8)));
typedef _Float16 half4_t __attribute__((ext_vector_type(4)));
typedef float f32x4 __attribute__((ext_vector_type(4)));

#define BM 128
#define BN 128
#define BK 32
#define LDT 40   // padded LDS row (f16) to break bank conflicts

// ---------------------------------------------------------------------------
// f16-plane MFMA GEMM, NT: acc[m][n] = sum_k A[m][k]*B[n][k] over pass set:
//   always Ahi*Bhi; +Ahi*Blo if LB==2; +Alo*Bhi if LA==2  (lo*lo dropped)
// AF32: A is f32, converted inline to exact integer codes via *(1/|preAp|).
// Epilogue: se = scale_c * |sc1| * |sc2|.
//   qmode 0: store f32 acc*se
//   qmode 1: store f16 code rint(clip(acc*se/|sPtr|, -128,127))
//   qmode 2: store f16 code rint(clip(acc*se/|sPtr|, 0,255))
// causal: skip blocks above diagonal. triK: K capped at m0+BM.
// ---------------------------------------------------------------------------
template<int LA, int LB, bool AF32>
__global__ __launch_bounds__(256)
void gemm_f16(const void* __restrict__ Ap, const _Float16* __restrict__ Alo,
              int lda, long long strA,
              const _Float16* __restrict__ Bhi, const _Float16* __restrict__ Blo,
              int ldb, long long strB, int divB,
              void* __restrict__ Cp, int ldc, long long strC,
              int K, float scale_c, const float* sc1, const float* sc2,
              const float* preAp,
              int qmode, const float* sPtr,
              int causal, int triK)
{
    int bz = blockIdx.z;
    int m0 = blockIdx.y * BM, n0 = blockIdx.x * BN;
    if (causal && n0 > m0 + (BM - 1)) return;
    int Keff = K;
    if (triK && (m0 + BM) < Keff) Keff = m0 + BM;

    const _Float16* Ahi = (const _Float16*)Ap + (AF32 ? 0 : bz * strA);
    const _Float16* AloP = Alo + (LA == 2 ? bz * strA : 0);
    const float* Af = (const float*)Ap + (AF32 ? bz * strA : 0);
    const _Float16* BhiP = Bhi + (long long)(bz / divB) * strB;
    const _Float16* BloP = (LB == 2) ? Blo + (long long)(bz / divB) * strB : nullptr;
    float* Cf = (float*)Cp + bz * strC;
    _Float16* Ch = (_Float16*)Cp + bz * strC;

    float preA = 1.f;
    if (AF32) preA = 1.f / fabsf(preAp[0]);

    __shared__ _Float16 As[LA][BM][LDT];
    __shared__ _Float16 Bs[LB][BN][LDT];

    int t = threadIdx.x;
    int srow = t >> 2;           // 0..63
    int scol = (t & 3) * 8;      // 0,8,16,24
    int w = t >> 6, lane = t & 63;
    int wm = (w >> 1) * 64, wn = (w & 1) * 64;
    int lr = lane & 15, lg = lane >> 4;

    f32x4 acc[4][4];
    #pragma unroll
    for (int i = 0; i < 4; ++i)
        #pragma unroll
        for (int j = 0; j < 4; ++j)
            acc[i][j] = (f32x4){0.f, 0.f, 0.f, 0.f};

    for (int k0 = 0; k0 < Keff; k0 += BK) {
        half8_t aH[2], aL[2], bH[2], bL[2];
        f32x4 aF[2][2];
        #pragma unroll
        for (int rep = 0; rep < 2; ++rep) {
            int row = rep * 64 + srow;
            long long ai = (long long)(m0 + row) * lda + k0 + scol;
            long long bi = (long long)(n0 + row) * ldb + k0 + scol;
            if constexpr (AF32) {
                aF[rep][0] = *(const f32x4*)&Af[ai];
                aF[rep][1] = *(const f32x4*)&Af[ai + 4];
            } else {
                aH[rep] = *(const half8_t*)&Ahi[ai];
                if constexpr (LA == 2) aL[rep] = *(const half8_t*)&AloP[ai];
            }
            bH[rep] = *(const half8_t*)&BhiP[bi];
            if constexpr (LB == 2) bL[rep] = *(const half8_t*)&BloP[bi];
        }
        __syncthreads();   // prior tile fully consumed
        #pragma unroll
        for (int rep = 0; rep < 2; ++rep) {
            int row = rep * 64 + srow;
            if constexpr (AF32) {
                half8_t h;
                #pragma unroll
                for (int e = 0; e < 4; ++e) {
                    h[e]     = (_Float16)(aF[rep][0][e] * preA);
                    h[e + 4] = (_Float16)(aF[rep][1][e] * preA);
                }
                *(half8_t*)&As[0][row][scol] = h;
            } else {
                *(half8_t*)&As[0][row][scol] = aH[rep];
                if constexpr (LA == 2) *(half8_t*)&As[1][row][scol] = aL[rep];
            }
            *(half8_t*)&Bs[0][row][scol] = bH[rep];
            if constexpr (LB == 2) *(half8_t*)&Bs[1][row][scol] = bL[rep];
        }
        __syncthreads();

        half8_t a0[4], b0[4];
        #pragma unroll
        for (int i = 0; i < 4; ++i) a0[i] = *(const half8_t*)&As[0][wm + i*16 + lr][lg*8];
        #pragma unroll
        for (int j = 0; j < 4; ++j) b0[j] = *(const half8_t*)&Bs[0][wn + j*16 + lr][lg*8];
        #pragma unroll
        for (int i = 0; i < 4; ++i)
            #pragma unroll
            for (int j = 0; j < 4; ++j)
                acc[i][j] = __builtin_amdgcn_mfma_f32_16x16x32_f16(a0[i], b0[j], acc[i][j], 0, 0, 0);
        if constexpr (LB == 2) {
            half8_t b1[4];
            #pragma unroll
            for (int j = 0; j < 4; ++j) b1[j] = *(const half8_t*)&Bs[1][wn + j*16 + lr][lg*8];
            #pragma unroll
            for (int i = 0; i < 4; ++i)
                #pragma unroll
                for (int j = 0; j < 4; ++j)
                    acc[i][j] = __builtin_amdgcn_mfma_f32_16x16x32_f16(a0[i], b1[j], acc[i][j], 0, 0, 0);
        }
        if constexpr (LA == 2) {
            half8_t a1[4];
            #pragma unroll
            for (int i = 0; i < 4; ++i) a1[i] = *(const half8_t*)&As[1][wm + i*16 + lr][lg*8];
            #pragma unroll
            for (int i = 0; i < 4; ++i)
                #pragma unroll
                for (int j = 0; j < 4; ++j)
                    acc[i][j] = __builtin_amdgcn_mfma_f32_16x16x32_f16(a1[i], b0[j], acc[i][j], 0, 0, 0);
        }
    }

    float se = scale_c;
    if (sc1) se *= fabsf(sc1[0]);
    if (sc2) se *= fabsf(sc2[0]);
    float sv = sPtr ? fabsf(sPtr[0]) : 1.f;

    #pragma unroll
    for (int i = 0; i < 4; ++i)
        #pragma unroll
        for (int j = 0; j < 4; ++j)
            #pragma unroll
            for (int r = 0; r < 4; ++r) {
                long long row = m0 + wm + i * 16 + lg * 4 + r;
                long long col = n0 + wn + j * 16 + lr;
                float v = acc[i][j][r] * se;
                if (qmode == 0) {
                    Cf[row * (long long)ldc + col] = v;
                } else if (qmode == 1) {
                    float u = rintf(fminf(fmaxf(v / sv, -128.f), 127.f));
                    Ch[row * (long long)ldc + col] = (_Float16)u;
                } else {
                    float u = rintf(fminf(fmaxf(v / sv, 0.f), 255.f));
                    Ch[row * (long long)ldc + col] = (_Float16)u;
                }
            }
}

// ---------------------------------------------------------------------------
// f32 -> f16 hi/lo split (vectorized x4), one-shot per operand
// ---------------------------------------------------------------------------
__global__ void split_f16(const float* __restrict__ in, _Float16* __restrict__ hi,
                          _Float16* __restrict__ lo, int n4)
{
    int i = blockIdx.x * 256 + threadIdx.x;
    if (i >= n4) return;
    f32x4 v = ((const f32x4*)in)[i];
    half4_t h, l;
    #pragma unroll
    for (int e = 0; e < 4; ++e) {
        h[e] = (_Float16)v[e];
        l[e] = (_Float16)(v[e] - (float)h[e]);
    }
    ((half4_t*)hi)[i] = h;
    ((half4_t*)lo)[i] = l;
}

// ---------------------------------------------------------------------------
// RoPE on integer codes -> hi/lo f16 planes in code units: [nh][S][HD]
// ---------------------------------------------------------------------------
__global__ void rope_f16(const _Float16* __restrict__ codes,
                         const float* __restrict__ cosT,
                         const float* __restrict__ sinT,
                         _Float16* __restrict__ ohi, _Float16* __restrict__ olo, int nh)
{
    long long idx = (long long)blockIdx.x * 256 + threadIdx.x;
    int d = idx & (HD - 1);
    long long tt = idx >> 7;     // s*nh + h
    int h = (int)(tt % nh);
    int s = (int)(tt / nh);
    float x = (float)codes[idx];
    float other = (d < 64) ? -(float)codes[idx + 64] : (float)codes[idx - 64];
    float o = x * cosT[s * HD + d] + other * sinT[s * HD + d];
    _Float16 hf = (_Float16)o;
    long long oi = ((long long)h * S_LEN + s) * HD + d;
    ohi[oi] = hf;
    olo[oi] = (_Float16)(o - (float)hf);
}

// ---------------------------------------------------------------------------
// v codes transpose: [S][KVH*HD] -> [kvh][HD][S]
// ---------------------------------------------------------------------------
__global__ __launch_bounds__(256)
void transpose_vf16(const _Float16* __restrict__ in, _Float16* __restrict__ outp)
{
    __shared__ _Float16 tile[64][72];
    int s0 = blockIdx.x * 64, d0 = blockIdx.y * 64, h = blockIdx.z;
    int t = threadIdx.x;
    int rr = t >> 4, cc = (t & 15) * 4;
    #pragma unroll
    for (int r = 0; r < 4; ++r) {
        half4_t v = *(const half4_t*)&in[(long long)(s0 + rr + 16*r) * KD + h * HD + d0 + cc];
        *(half4_t*)&tile[rr + 16*r][cc] = v;
    }
    __syncthreads();
    #pragma unroll
    for (int r = 0; r < 4; ++r) {
        int dr = rr + 16 * r;
        half4_t o = { tile[cc+0][dr], tile[cc+1][dr], tile[cc+2][dr], tile[cc+3][dr] };
        *(half4_t*)&outp[((long long)h * HD + d0 + dr) * S_LEN + s0 + cc] = o;
    }
}

// ---------------------------------------------------------------------------
// Row softmax + LSQ(asym, s_attn) in place; zero-fills upper triangle.
// ---------------------------------------------------------------------------
__global__ __launch_bounds__(256)
void softmax_quant(float* __restrict__ attn, const float* __restrict__ sPtr)
{
    int row = blockIdx.x;            // h*S + q
    int q = row & (S_LEN - 1);
    float* p = attn + (long long)row * S_LEN;
    int n = q + 1;
    int tid = threadIdx.x;

    __shared__ float buf[S_LEN];
    __shared__ float swm[4];
    __shared__ float sws[4];

    float mx = -INFINITY;
    for (int i = tid; i < n; i += 256) {
        float v = p[i];
        buf[i] = v;
        mx = fmaxf(mx, v);
    }
    #pragma unroll
    for (int o = 32; o; o >>= 1) mx = fmaxf(mx, __shfl_xor(mx, o));
    if ((tid & 63) == 0) swm[tid >> 6] = mx;
    __syncthreads();
    mx = fmaxf(fmaxf(swm[0], swm[1]), fmaxf(swm[2], swm[3]));

    float lsum = 0.f;
    for (int i = tid; i < n; i += 256) {
        float e = expf(buf[i] - mx);
        buf[i] = e;
        lsum += e;
    }
    #pragma unroll
    for (int o = 32; o; o >>= 1) lsum += __shfl_xor(lsum, o);
    if ((tid & 63) == 0) sws[tid >> 6] = lsum;
    __syncthreads();
    float tot = sws[0] + sws[1] + sws[2] + sws[3];

    float sa = fabsf(sPtr[0]);
    for (int i = tid; i < n; i += 256) {
        float pr = buf[i] / tot;
        float t = fminf(fmaxf(pr / sa, 0.f), 255.f);
        p[i] = rintf(t) * sa;
    }
    for (int i = tid; i < S_LEN; i += 256)
        if (i >= n) p[i] = 0.f;
}

extern "C" void kernel_launch(void* const* d_in, const int* in_sizes, int n_in,
                              void* d_out, int out_size, void* d_ws, size_t ws_size,
                              hipStream_t stream)
{
    const float* hs    = (const float*)d_in[0];
    const float* Wq    = (const float*)d_in[1];
    const float* Wk    = (const float*)d_in[2];
    const float* Wv    = (const float*)d_in[3];
    const float* Wo    = (const float*)d_in[4];
    const float* s_q   = (const float*)d_in[5];
    const float* s_k   = (const float*)d_in[6];
    const float* s_v   = (const float*)d_in[7];
    const float* s_at  = (const float*)d_in[8];
    const float* s_out = (const float*)d_in[9];
    const float* cosT  = (const float*)d_in[10];
    const float* sinT  = (const float*)d_in[11];
    // d_in[12] = attention_mask: pure causal, applied structurally.

    float* out  = (float*)d_out;                         // [S][2048]
    float* attn = out + (long long)S_LEN * HID_DIM;      // [16][S][S]

    const long long M4 = 4LL * 1024 * 1024;
    const long long M1 = 1LL * 1024 * 1024;

    // ws (46 MB): planes that must survive past the scores GEMM.
    _Float16* wsh   = (_Float16*)d_ws;
    _Float16* qr_hi = wsh;            // NH*S*HD  = 4M
    _Float16* qr_lo = qr_hi + M4;
    _Float16* kr_hi = qr_lo + M4;     // NKVH*S*HD = 1M
    _Float16* kr_lo = kr_hi + M1;
    _Float16* vT    = kr_lo + M1;     // 1M
    _Float16* ao    = vT + M1;        // S*QD = 4M
    _Float16* Wo_hi = ao + M4;        // 4M
    _Float16* Wo_lo = Wo_hi + M4;     // 4M

    // Pre-scores scratch parked inside the attn region (consumed before
    // scores overwrites it): 26M f16 = 52 MB < 256 MB.
    _Float16* sc    = (_Float16*)attn;
    _Float16* hs_hi = sc;             // 4M
    _Float16* hs_lo = hs_hi + M4;
    _Float16* Wq_hi = hs_lo + M4;     // 4M
    _Float16* Wq_lo = Wq_hi + M4;
    _Float16* Wk_hi = Wq_lo + M4;     // 1M
    _Float16* Wk_lo = Wk_hi + M1;
    _Float16* Wv_hi = Wk_lo + M1;
    _Float16* Wv_lo = Wv_hi + M1;
    _Float16* qcode = Wv_lo + M1;     // 4M
    _Float16* kcode = qcode + M4;     // 1M
    _Float16* vcode = kcode + M1;     // 1M

    dim3 blk(256);
    const float iscale = 0.08838834764831845f;  // 1/sqrt(128)

    // 0) one-shot f32 -> f16 hi/lo splits
    split_f16<<<4096, blk, 0, stream>>>(hs, hs_hi, hs_lo, 1024*1024);
    split_f16<<<4096, blk, 0, stream>>>(Wq, Wq_hi, Wq_lo, 1024*1024);
    split_f16<<<1024, blk, 0, stream>>>(Wk, Wk_hi, Wk_lo, 256*1024);
    split_f16<<<1024, blk, 0, stream>>>(Wv, Wv_hi, Wv_lo, 256*1024);
    split_f16<<<4096, blk, 0, stream>>>(Wo, Wo_hi, Wo_lo, 1024*1024);

    // 1) QKV projections -> integer codes (f16), 3-pass split GEMM
    gemm_f16<2,2,false><<<dim3(QD/BN, S_LEN/BM, 1), blk, 0, stream>>>(
        hs_hi, hs_lo, HID_DIM, 0, Wq_hi, Wq_lo, HID_DIM, 0, 1,
        qcode, QD, 0, HID_DIM, 1.f, nullptr, nullptr, nullptr, 1, s_q, 0, 0);
    gemm_f16<2,2,false><<<dim3(KD/BN, S_LEN/BM, 1), blk, 0, stream>>>(
        hs_hi, hs_lo, HID_DIM, 0, Wk_hi, Wk_lo, HID_DIM, 0, 1,
        kcode, KD, 0, HID_DIM, 1.f, nullptr, nullptr, nullptr, 1, s_k, 0, 0);
    gemm_f16<2,2,false><<<dim3(KD/BN, S_LEN/BM, 1), blk, 0, stream>>>(
        hs_hi, hs_lo, HID_DIM, 0, Wv_hi, Wv_lo, HID_DIM, 0, 1,
        vcode, KD, 0, HID_DIM, 1.f, nullptr, nullptr, nullptr, 1, s_v, 0, 0);

    // 2) RoPE (code units) -> hi/lo planes; v codes -> [kvh][HD][S]
    rope_f16<<<(S_LEN*QD)/256, blk, 0, stream>>>(qcode, cosT, sinT, qr_hi, qr_lo, NH);
    rope_f16<<<(S_LEN*KD)/256, blk, 0, stream>>>(kcode, cosT, sinT, kr_hi, kr_lo, NKVH);
    transpose_vf16<<<dim3(S_LEN/64, HD/64, NKVH), blk, 0, stream>>>(vcode, vT);

    // 3) scores = (qr . kr) * s_q*s_k/sqrt(HD), causal block skip, f32 out
    gemm_f16<2,2,false><<<dim3(S_LEN/BN, S_LEN/BM, NH), blk, 0, stream>>>(
        qr_hi, qr_lo, HD, (long long)S_LEN*HD,
        kr_hi, kr_lo, HD, (long long)S_LEN*HD, NH/NKVH,
        attn, S_LEN, (long long)S_LEN*S_LEN,
        HD, iscale, s_q, s_k, nullptr, 0, nullptr, 1, 0);

    // 4) softmax + LSQ(asym) in place
    softmax_quant<<<NH*S_LEN, blk, 0, stream>>>(attn, s_at);

    // 5) PV: attn(f32->codes inline) x vT codes, exact; ao codes f16 out
    gemm_f16<1,1,true><<<dim3(1, S_LEN/BM, NH), blk, 0, stream>>>(
        attn, nullptr, S_LEN, (long long)S_LEN*S_LEN,
        vT, nullptr, S_LEN, (long long)HD*S_LEN, NH/NKVH,
        ao, QD, HD,
        S_LEN, 1.f, s_at, s_v, s_at, 2, s_out, 0, 1);

    // 6) out = (ao codes @ Wo^T) * s_out, 2-pass (A exact)
    gemm_f16<1,2,false><<<dim3(HID_DIM/BN, S_LEN/BM, 1), blk, 0, stream>>>(
        ao, nullptr, QD, 0, Wo_hi, Wo_lo, QD, 0, 1,
        out, HID_DIM, 0, QD, 1.f, s_out, nullptr, nullptr, 0, nullptr, 0, 0);
}

// Round 5
// 493.126 us; speedup vs baseline: 2.3161x; 1.2929x over previous
//
#include <hip/hip_runtime.h>
#include <math.h>

#define S_LEN 2048
#define HID_DIM 2048
#define NH 16
#define NKVH 4
#define HD 128
#define QD (NH*HD)    // 2048
#define KD (NKVH*HD)  // 512
#define NQKV 3072     // Q(2048) | K(512) | V(512)

typedef _Float16 half8_t __attribute__((ext_vector_type(8)));
typedef _Float16 half4_t __attribute__((ext_vector_type(4)));
typedef float f32x4 __attribute__((ext_vector_type(4)));

#define BM 128
#define BN 128
#define BK 32

typedef const __attribute__((address_space(1))) char gas_char;
typedef __attribute__((address_space(3))) char las_char;
#define GL16(gp, lp) __builtin_amdgcn_global_load_lds((gas_char*)(gp), (las_char*)(lp), 16, 0, 0)

// ---------------------------------------------------------------------------
// f16-plane MFMA GEMM, NT: acc[m][n] = sum_k A[m][k]*B[n][k] over pass set:
//   always Ahi*Bhi; +Ahi*Blo if LB==2; +Alo*Bhi if LA==2  (lo*lo dropped).
// Staging: global_load_lds direct to linear LDS [128][32] f16 per plane,
//   with XOR chunk swizzle (phys = logical ^ ((row>>1)&3)) applied on the
//   global source address and on the fragment ds_read (rule: both sides).
// AF32: A is f32, inline-converted to exact codes via *(1/|preAp|), reg-staged.
// Epilogue: se = scale_c * |sc1| * |sc2|.
//   qmode 0: f32 store acc*se
//   qmode 1: f16 code rint(clip(acc*se/|q1|, -128,127))
//   qmode 2: f16 code rint(clip(acc*se/|q1|, 0,255))
//   qmode 3: like 1, scale selected by n0: <2048 q1, <2560 q2, else q3
// causal: skip blocks above diagonal. triK: K capped at m0+BM.
// ---------------------------------------------------------------------------
template<int LA, int LB, bool AF32>
__global__ __launch_bounds__(256)
void gemm_f16(const void* __restrict__ Ap, const _Float16* __restrict__ Alo,
              int lda, long long strA,
              const _Float16* __restrict__ Bhi, const _Float16* __restrict__ Blo,
              int ldb, long long strB, int divB,
              void* __restrict__ Cp, int ldc, long long strC,
              int K, float scale_c, const float* sc1, const float* sc2,
              const float* preAp,
              int qmode, const float* q1, const float* q2, const float* q3,
              int causal, int triK)
{
    int bz = blockIdx.z;
    int m0 = blockIdx.y * BM, n0 = blockIdx.x * BN;
    if (causal && n0 > m0 + (BM - 1)) return;
    int Keff = K;
    if (triK && (m0 + BM) < Keff) Keff = m0 + BM;

    const _Float16* Ahi = AF32 ? nullptr : (const _Float16*)Ap + bz * strA;
    const _Float16* AloP = (LA == 2) ? Alo + bz * strA : nullptr;
    const float* Af = AF32 ? (const float*)Ap + bz * strA : nullptr;
    const _Float16* BhiP = Bhi + (long long)(bz / divB) * strB;
    const _Float16* BloP = (LB == 2) ? Blo + (long long)(bz / divB) * strB : nullptr;
    float* Cf = (float*)Cp + bz * strC;
    _Float16* Ch = (_Float16*)Cp + bz * strC;

    float preA = 1.f;
    if (AF32) preA = 1.f / fabsf(preAp[0]);

    // planes: A-hi [, A-lo], B-hi [, B-lo]; each 128*32 f16 = 4096 elems
    __shared__ _Float16 lds[(LA + LB) * 4096];
    _Float16* As0 = lds;
    _Float16* As1 = lds + 4096;              // valid iff LA==2
    _Float16* Bs0 = lds + LA * 4096;
    _Float16* Bs1 = lds + (LA + 1) * 4096;   // valid iff LB==2

    int t = threadIdx.x;
    int srow = t >> 2;                 // staging row 0..63 (+64 for rep 1)
    int gsw = (srow >> 1) & 3;         // swizzle constant for staging rows
    int gc = ((t & 3) ^ gsw) * 8;      // swizzled global chunk (elems)
    int w = t >> 6, lane = t & 63;
    int wm = (w >> 1) * 64, wn = (w & 1) * 64;
    int lr = lane & 15, lg = lane >> 4;
    int fco = ((lg ^ ((lr >> 1) & 3))) * 8;  // swizzled fragment chunk (elems)

    f32x4 acc[4][4];
    #pragma unroll
    for (int i = 0; i < 4; ++i)
        #pragma unroll
        for (int j = 0; j < 4; ++j)
            acc[i][j] = (f32x4){0.f, 0.f, 0.f, 0.f};

    for (int k0 = 0; k0 < Keff; k0 += BK) {
        f32x4 aF[2][2];
        if constexpr (AF32) {
            #pragma unroll
            for (int rep = 0; rep < 2; ++rep) {
                long long ai = (long long)(m0 + rep * 64 + srow) * lda + k0 + gc;
                aF[rep][0] = *(const f32x4*)&Af[ai];
                aF[rep][1] = *(const f32x4*)&Af[ai + 4];
            }
        }
        __syncthreads();   // prior tile fully consumed
        #pragma unroll
        for (int rep = 0; rep < 2; ++rep) {
            int row = rep * 64 + srow;
            int lo = rep * 2048 + t * 8;   // linear LDS slot (elems)
            if constexpr (!AF32) {
                long long ai = (long long)(m0 + row) * lda + k0 + gc;
                GL16(Ahi + ai, As0 + lo);
                if constexpr (LA == 2) GL16(AloP + ai, As1 + lo);
            }
            long long bi = (long long)(n0 + row) * ldb + k0 + gc;
            GL16(BhiP + bi, Bs0 + lo);
            if constexpr (LB == 2) GL16(BloP + bi, Bs1 + lo);
        }
        if constexpr (AF32) {
            #pragma unroll
            for (int rep = 0; rep < 2; ++rep) {
                half8_t h;
                #pragma unroll
                for (int e = 0; e < 4; ++e) {
                    h[e]     = (_Float16)(aF[rep][0][e] * preA);
                    h[e + 4] = (_Float16)(aF[rep][1][e] * preA);
                }
                *(half8_t*)&As0[rep * 2048 + t * 8] = h;
            }
        }
        __syncthreads();   // drains vmcnt (gload_lds) + lgkm (ds_write)

        half8_t a0[4], b0[4];
        #pragma unroll
        for (int i = 0; i < 4; ++i) a0[i] = *(const half8_t*)&As0[(wm + i*16 + lr) * 32 + fco];
        #pragma unroll
        for (int j = 0; j < 4; ++j) b0[j] = *(const half8_t*)&Bs0[(wn + j*16 + lr) * 32 + fco];
        #pragma unroll
        for (int i = 0; i < 4; ++i)
            #pragma unroll
            for (int j = 0; j < 4; ++j)
                acc[i][j] = __builtin_amdgcn_mfma_f32_16x16x32_f16(a0[i], b0[j], acc[i][j], 0, 0, 0);
        if constexpr (LB == 2) {
            half8_t b1[4];
            #pragma unroll
            for (int j = 0; j < 4; ++j) b1[j] = *(const half8_t*)&Bs1[(wn + j*16 + lr) * 32 + fco];
            #pragma unroll
            for (int i = 0; i < 4; ++i)
                #pragma unroll
                for (int j = 0; j < 4; ++j)
                    acc[i][j] = __builtin_amdgcn_mfma_f32_16x16x32_f16(a0[i], b1[j], acc[i][j], 0, 0, 0);
        }
        if constexpr (LA == 2) {
            half8_t a1[4];
            #pragma unroll
            for (int i = 0; i < 4; ++i) a1[i] = *(const half8_t*)&As1[(wm + i*16 + lr) * 32 + fco];
            #pragma unroll
            for (int i = 0; i < 4; ++i)
                #pragma unroll
                for (int j = 0; j < 4; ++j)
                    acc[i][j] = __builtin_amdgcn_mfma_f32_16x16x32_f16(a1[i], b0[j], acc[i][j], 0, 0, 0);
        }
    }

    float se = scale_c;
    if (sc1) se *= fabsf(sc1[0]);
    if (sc2) se *= fabsf(sc2[0]);
    float sv = 1.f;
    if (qmode == 3) {
        const float* sp = (n0 < 2048) ? q1 : ((n0 < 2560) ? q2 : q3);
        sv = fabsf(sp[0]);
        qmode = 1;
    } else if (qmode) {
        sv = fabsf(q1[0]);
    }

    #pragma unroll
    for (int i = 0; i < 4; ++i)
        #pragma unroll
        for (int j = 0; j < 4; ++j)
            #pragma unroll
            for (int r = 0; r < 4; ++r) {
                long long row = m0 + wm + i * 16 + lg * 4 + r;
                long long col = n0 + wn + j * 16 + lr;
                float v = acc[i][j][r] * se;
                if (qmode == 0) {
                    Cf[row * (long long)ldc + col] = v;
                } else if (qmode == 1) {
                    float u = rintf(fminf(fmaxf(v / sv, -128.f), 127.f));
                    Ch[row * (long long)ldc + col] = (_Float16)u;
                } else {
                    float u = rintf(fminf(fmaxf(v / sv, 0.f), 255.f));
                    Ch[row * (long long)ldc + col] = (_Float16)u;
                }
            }
}

// ---------------------------------------------------------------------------
// f32 -> f16 hi/lo split (vectorized x4), one-shot per operand
// ---------------------------------------------------------------------------
__global__ void split_f16(const float* __restrict__ in, _Float16* __restrict__ hi,
                          _Float16* __restrict__ lo, int n4)
{
    int i = blockIdx.x * 256 + threadIdx.x;
    if (i >= n4) return;
    f32x4 v = ((const f32x4*)in)[i];
    half4_t h, l;
    #pragma unroll
    for (int e = 0; e < 4; ++e) {
        h[e] = (_Float16)v[e];
        l[e] = (_Float16)(v[e] - (float)h[e]);
    }
    ((half4_t*)hi)[i] = h;
    ((half4_t*)lo)[i] = l;
}

// ---------------------------------------------------------------------------
// RoPE on integer codes (strided source) -> hi/lo f16 planes: [nh][S][HD]
// ---------------------------------------------------------------------------
__global__ void rope_f16(const _Float16* __restrict__ codes, int ldc_, int colOff,
                         const float* __restrict__ cosT,
                         const float* __restrict__ sinT,
                         _Float16* __restrict__ ohi, _Float16* __restrict__ olo, int nh)
{
    long long idx = (long long)blockIdx.x * 256 + threadIdx.x;
    int d = idx & (HD - 1);
    long long tt = idx >> 7;     // s*nh + h
    int h = (int)(tt % nh);
    int s = (int)(tt / nh);
    long long base = (long long)s * ldc_ + colOff + h * HD;
    float x = (float)codes[base + d];
    float other = (d < 64) ? -(float)codes[base + d + 64] : (float)codes[base + d - 64];
    float o = x * cosT[s * HD + d] + other * sinT[s * HD + d];
    _Float16 hf = (_Float16)o;
    long long oi = ((long long)h * S_LEN + s) * HD + d;
    ohi[oi] = hf;
    olo[oi] = (_Float16)(o - (float)hf);
}

// ---------------------------------------------------------------------------
// v codes transpose: qkvcode[S][3072] cols 2560.. -> vT [kvh][HD][S]
// ---------------------------------------------------------------------------
__global__ __launch_bounds__(256)
void transpose_vf16(const _Float16* __restrict__ in, _Float16* __restrict__ outp)
{
    __shared__ _Float16 tile[64][72];
    int s0 = blockIdx.x * 64, d0 = blockIdx.y * 64, h = blockIdx.z;
    int t = threadIdx.x;
    int rr = t >> 4, cc = (t & 15) * 4;
    #pragma unroll
    for (int r = 0; r < 4; ++r) {
        half4_t v = *(const half4_t*)&in[(long long)(s0 + rr + 16*r) * NQKV + 2560 + h * HD + d0 + cc];
        *(half4_t*)&tile[rr + 16*r][cc] = v;
    }
    __syncthreads();
    #pragma unroll
    for (int r = 0; r < 4; ++r) {
        int dr = rr + 16 * r;
        half4_t o = { tile[cc+0][dr], tile[cc+1][dr], tile[cc+2][dr], tile[cc+3][dr] };
        *(half4_t*)&outp[((long long)h * HD + d0 + dr) * S_LEN + s0 + cc] = o;
    }
}

// ---------------------------------------------------------------------------
// Row softmax + LSQ(asym, s_attn) in place; zero-fills upper triangle.
// ---------------------------------------------------------------------------
__global__ __launch_bounds__(256)
void softmax_quant(float* __restrict__ attn, const float* __restrict__ sPtr)
{
    int row = blockIdx.x;            // h*S + q
    int q = row & (S_LEN - 1);
    float* p = attn + (long long)row * S_LEN;
    int n = q + 1;
    int tid = threadIdx.x;

    __shared__ float buf[S_LEN];
    __shared__ float swm[4];
    __shared__ float sws[4];

    float mx = -INFINITY;
    for (int i = tid; i < n; i += 256) {
        float v = p[i];
        buf[i] = v;
        mx = fmaxf(mx, v);
    }
    #pragma unroll
    for (int o = 32; o; o >>= 1) mx = fmaxf(mx, __shfl_xor(mx, o));
    if ((tid & 63) == 0) swm[tid >> 6] = mx;
    __syncthreads();
    mx = fmaxf(fmaxf(swm[0], swm[1]), fmaxf(swm[2], swm[3]));

    float lsum = 0.f;
    for (int i = tid; i < n; i += 256) {
        float e = expf(buf[i] - mx);
        buf[i] = e;
        lsum += e;
    }
    #pragma unroll
    for (int o = 32; o; o >>= 1) lsum += __shfl_xor(lsum, o);
    if ((tid & 63) == 0) sws[tid >> 6] = lsum;
    __syncthreads();
    float tot = sws[0] + sws[1] + sws[2] + sws[3];

    float sa = fabsf(sPtr[0]);
    for (int i = tid; i < n; i += 256) {
        float pr = buf[i] / tot;
        float t = fminf(fmaxf(pr / sa, 0.f), 255.f);
        p[i] = rintf(t) * sa;
    }
    for (int i = tid; i < S_LEN; i += 256)
        if (i >= n) p[i] = 0.f;
}

extern "C" void kernel_launch(void* const* d_in, const int* in_sizes, int n_in,
                              void* d_out, int out_size, void* d_ws, size_t ws_size,
                              hipStream_t stream)
{
    const float* hs    = (const float*)d_in[0];
    const float* Wq    = (const float*)d_in[1];
    const float* Wk    = (const float*)d_in[2];
    const float* Wv    = (const float*)d_in[3];
    const float* Wo    = (const float*)d_in[4];
    const float* s_q   = (const float*)d_in[5];
    const float* s_k   = (const float*)d_in[6];
    const float* s_v   = (const float*)d_in[7];
    const float* s_at  = (const float*)d_in[8];
    const float* s_out = (const float*)d_in[9];
    const float* cosT  = (const float*)d_in[10];
    const float* sinT  = (const float*)d_in[11];
    // d_in[12] = attention_mask: pure causal, applied structurally.

    float* out  = (float*)d_out;                         // [S][2048]
    float* attn = out + (long long)S_LEN * HID_DIM;      // [16][S][S]

    const long long M1 = 1LL * 1024 * 1024;
    const long long M4 = 4LL * M1;
    const long long M6 = 6LL * M1;

    // ws (46 MB): planes that must survive past the scores GEMM.
    _Float16* wsh   = (_Float16*)d_ws;
    _Float16* qr_hi = wsh;            // NH*S*HD  = 4M
    _Float16* qr_lo = qr_hi + M4;
    _Float16* kr_hi = qr_lo + M4;     // NKVH*S*HD = 1M
    _Float16* kr_lo = kr_hi + M1;
    _Float16* vT    = kr_lo + M1;     // 1M
    _Float16* ao    = vT + M1;        // S*QD = 4M
    _Float16* Wo_hi = ao + M4;        // 4M
    _Float16* Wo_lo = Wo_hi + M4;     // 4M

    // Pre-scores scratch parked inside the attn region (52 MB < 256 MB),
    // consumed before the scores GEMM overwrites it.
    _Float16* sc      = (_Float16*)attn;
    _Float16* hs_hi   = sc;             // 4M
    _Float16* hs_lo   = hs_hi + M4;     // 4M
    _Float16* Whi     = hs_lo + M4;     // [3072][2048] = 6M
    _Float16* Wlo     = Whi + M6;       // 6M
    _Float16* qkvcode = Wlo + M6;       // [S][3072] = 6M

    dim3 blk(256);
    const float iscale = 0.08838834764831845f;  // 1/sqrt(128)

    // 0) one-shot f32 -> f16 hi/lo splits (W planes stacked Q|K|V)
    split_f16<<<4096, blk, 0, stream>>>(hs, hs_hi, hs_lo, 1024*1024);
    split_f16<<<4096, blk, 0, stream>>>(Wq, Whi, Wlo, 1024*1024);
    split_f16<<<1024, blk, 0, stream>>>(Wk, Whi + 2048LL*2048, Wlo + 2048LL*2048, 256*1024);
    split_f16<<<1024, blk, 0, stream>>>(Wv, Whi + 2560LL*2048, Wlo + 2560LL*2048, 256*1024);
    split_f16<<<4096, blk, 0, stream>>>(Wo, Wo_hi, Wo_lo, 1024*1024);

    // 1) merged QKV projection -> integer codes f16 [S][3072]
    gemm_f16<2,2,false><<<dim3(NQKV/BN, S_LEN/BM, 1), blk, 0, stream>>>(
        hs_hi, hs_lo, HID_DIM, 0, Whi, Wlo, HID_DIM, 0, 1,
        qkvcode, NQKV, 0, HID_DIM, 1.f, nullptr, nullptr, nullptr,
        3, s_q, s_k, s_v, 0, 0);

    // 2) RoPE (code units) -> hi/lo planes; v codes -> [kvh][HD][S]
    rope_f16<<<(NH*S_LEN*HD)/256, blk, 0, stream>>>(qkvcode, NQKV, 0, cosT, sinT, qr_hi, qr_lo, NH);
    rope_f16<<<(NKVH*S_LEN*HD)/256, blk, 0, stream>>>(qkvcode, NQKV, 2048, cosT, sinT, kr_hi, kr_lo, NKVH);
    transpose_vf16<<<dim3(S_LEN/64, HD/64, NKVH), blk, 0, stream>>>(qkvcode, vT);

    // 3) scores = (qr . kr) * s_q*s_k/sqrt(HD), causal block skip, f32 out
    gemm_f16<2,2,false><<<dim3(S_LEN/BN, S_LEN/BM, NH), blk, 0, stream>>>(
        qr_hi, qr_lo, HD, (long long)S_LEN*HD,
        kr_hi, kr_lo, HD, (long long)S_LEN*HD, NH/NKVH,
        attn, S_LEN, (long long)S_LEN*S_LEN,
        HD, iscale, s_q, s_k, nullptr, 0, nullptr, nullptr, nullptr, 1, 0);

    // 4) softmax + LSQ(asym) in place
    softmax_quant<<<NH*S_LEN, blk, 0, stream>>>(attn, s_at);

    // 5) PV: attn(f32->codes inline) x vT codes, exact; ao codes f16 out
    gemm_f16<1,1,true><<<dim3(1, S_LEN/BM, NH), blk, 0, stream>>>(
        attn, nullptr, S_LEN, (long long)S_LEN*S_LEN,
        vT, nullptr, S_LEN, (long long)HD*S_LEN, NH/NKVH,
        ao, QD, HD,
        S_LEN, 1.f, s_at, s_v, s_at, 2, s_out, nullptr, nullptr, 0, 1);

    // 6) out = (ao codes @ Wo^T) * s_out, 2-pass (A exact)
    gemm_f16<1,2,false><<<dim3(HID_DIM/BN, S_LEN/BM, 1), blk, 0, stream>>>(
        ao, nullptr, QD, 0, Wo_hi, Wo_lo, QD, 0, 1,
        out, HID_DIM, 0, QD, 1.f, s_out, nullptr, nullptr,
        0, nullptr, nullptr, nullptr, 0, 0);
}